// Round 1
// 219.164 us; speedup vs baseline: 1.0297x; 1.0297x over previous
//
#include <hip/hip_runtime.h>
#include <hip/hip_bf16.h>
#include <math.h>

// Problem constants
#define BB 4
#define TT 2048
#define CC 1024
#define HH 16
#define DD 64
#define WW 256
#define MM (BB*TT)   // 8192 rows
#define NX (MM*CC)
#define NQ (3*CC*CC)
#define NP (CC*CC)

typedef __bf16 bf16x8 __attribute__((ext_vector_type(8)));
typedef __bf16 bf16x4 __attribute__((ext_vector_type(4)));
typedef float  f32x4  __attribute__((ext_vector_type(4)));

// async global->LDS 16B: LDS dest is wave-uniform base; HW adds lane*16
__device__ __forceinline__ void async_cp16(const void* g, void* l) {
  __builtin_amdgcn_global_load_lds(
      (const __attribute__((address_space(1))) void*)g,
      (__attribute__((address_space(3))) void*)l, 16, 0, 0);
}

__device__ __forceinline__ unsigned short f2bf(float v) {
  __hip_bfloat16 h = __float2bfloat16(v);
  return *(unsigned short*)&h;
}

// ---------------------------------------------------------------------------
// prep: fused (a) weight fp32->bf16 convert, (b) x convert+pack into
// MFMA A-fragment-major layout Apk[((rt*32+g)*64+lane)*8].
// ---------------------------------------------------------------------------
__global__ __launch_bounds__(256)
void prep(const float* __restrict__ x,
          const float* __restrict__ wq,
          const float* __restrict__ wp,
          __hip_bfloat16* __restrict__ wdst,
          unsigned short* __restrict__ Apk) {
  const int p = blockIdx.x;
  const int tid = threadIdx.x;
  if (p < 4096) {                       // ---- weight convert
    int i = (p * 256 + tid) * 4;
    const float* src; int off;
    if (i < NQ) { src = wq; off = i; }
    else        { src = wp; off = i - NQ; }
    float4 v = *(const float4*)(src + off);
    wdst[i + 0] = __float2bfloat16(v.x);
    wdst[i + 1] = __float2bfloat16(v.y);
    wdst[i + 2] = __float2bfloat16(v.z);
    wdst[i + 3] = __float2bfloat16(v.w);
    return;
  }
  // ---- x convert + pack (64 rows x 64 k per block)
  __shared__ __align__(16) unsigned short tile[64 * 72]; // stride 144B
  const int pid = p - 4096;
  const int bm = pid & 127;
  const int bk = pid >> 7;
  const int tr = tid >> 4;
  const int tc = (tid & 15) * 4;
#pragma unroll
  for (int i = 0; i < 4; i++) {
    int row = i * 16 + tr;
    float4 v = *(const float4*)&x[(size_t)(bm * 64 + row) * 1024 + bk * 64 + tc];
    tile[row * 72 + tc + 0] = f2bf(v.x);
    tile[row * 72 + tc + 1] = f2bf(v.y);
    tile[row * 72 + tc + 2] = f2bf(v.z);
    tile[row * 72 + tc + 3] = f2bf(v.w);
  }
  __syncthreads();
  const int w = tid >> 6, lane = tid & 63;
  const int quad = lane >> 4, l15 = lane & 15;
#pragma unroll
  for (int f = 0; f < 2; f++) {
    bf16x8 fr = *(const bf16x8*)&tile[(w * 16 + l15) * 72 + f * 32 + quad * 8];
    *(bf16x8*)&Apk[(((size_t)(bm * 4 + w) * 32) + bk * 2 + f) * 512 + lane * 8] = fr;
  }
}

// ---------------------------------------------------------------------------
// QKV GEMM (round 14): r13 datapath + DEEP-PIPELINED K-LOOP.
// BK=64 quad-buffer (4 x 16KB = same 64KB LDS, occupancy unchanged at
// 2 blk/CU). stageB issued 3 steps ahead; raw s_barrier with COUNTED
// s_waitcnt vmcnt(16) placed BEFORE the barrier (publishes this wave's
// stage(s+1) retirement to the group; never drains the 2 younger stages
// or the A-prefetch). lgkmcnt(0) per step covers the ds_read-vs-
// global_load_lds-overwrite hazard. setprio(1) brackets each MFMA
// cluster (T5: stage/wait/MFMA role-split now exists for the scheduler
// to arbitrate). r13's __syncthreads (vmcnt0 drain) exposed ~200-300cyc
// of Wqkv stage latency per step -> MfmaUtil stuck at 29.7%.
// vmcnt(16) derivation: ops in fence-regions strictly after stage(s+1)
// and before the wait >= st(s+2)4 + A(s-1)8 + st(s+3)4 + A(s)8 = 24;
// allowed-live = st(s+2)+st(s+3)+A(s) = 16. 16 <= 24 -> stage(s+1)
// provably retired; nothing younger force-drained.
// ---------------------------------------------------------------------------
__global__ __launch_bounds__(256, 2)
void gemm_qkv(const unsigned short* __restrict__ Apk,
              const unsigned short* __restrict__ Bw,
              unsigned short* __restrict__ Qh,
              unsigned short* __restrict__ Kh,
              unsigned short* __restrict__ Vt) {
  __shared__ __align__(16) unsigned short Bs[4][8192]; // 4 x 16 KB, BK=64

  const int id   = blockIdx.x;
  const int xcd  = id & 7;
  const int slot = id >> 3;        // 0..95
  const int mloc = slot / 24;      // 0..3   (XCD-local m-block)
  const int nloc = slot % 24;      // 0..23  (n-panels stream over L2-hot A)
  const int m0 = (xcd * 4 + mloc) * 256;
  const int n0 = nloc * 128;

  const int tid  = threadIdx.x;
  const int w    = tid >> 6;       // 0..3: row-block of 64
  const int lane = tid & 63;
  const int quad = lane >> 4;
  const int l15  = lane & 15;

  f32x4 acc[4][8];
#pragma unroll
  for (int i = 0; i < 4; i++)
#pragma unroll
    for (int j = 0; j < 8; j++) acc[i][j] = (f32x4)0.0f;

  const unsigned short* abase =
      Apk + ((size_t)((m0 >> 4) + w * 4) * 32) * 512 + lane * 8;

  // BK=64 stage: 16 KB per buffer -> 4 cp16 per wave
  auto stageB = [&](int k0, unsigned short* bs) {
#pragma unroll
    for (int i = 0; i < 4; i++) {
      int idx  = w + 4 * i;        // 0..15
      int kc   = idx >> 1;         // 0..7
      int half = idx & 1;
      async_cp16(Bw + (size_t)(n0 + half * 64 + lane) * 1024 + k0 + kc * 8,
                 &bs[kc * 1024 + half * 512]);
    }
  };

  bf16x8 Af[3][4];                 // depth-2 A prefetch ring (L2-hit ~200cyc)
  auto loadA = [&](int g, bf16x8* fr) {
#pragma unroll
    for (int tm = 0; tm < 4; tm++)
      fr[tm] = *(const bf16x8*)(abase + ((size_t)(tm * 32 + g)) * 512);
  };

  // prologue: A for g=0,1; stage buffers 0..2; one-time full drain
  loadA(0, Af[0]);
  loadA(1, Af[1]);
  stageB(0,   Bs[0]);
  stageB(64,  Bs[1]);
  stageB(128, Bs[2]);
  asm volatile("s_waitcnt vmcnt(0)" ::: "memory");
  __builtin_amdgcn_sched_barrier(0);
  asm volatile("s_barrier" ::: "memory");

#pragma unroll
  for (int s = 0; s < 16; s++) {
    const unsigned short* bs = Bs[s & 3];
    if (s + 3 < 16) stageB((s + 3) * 64, Bs[(s + 3) & 3]); // 3-deep prefetch
#pragma unroll
    for (int sub = 0; sub < 2; sub++) {
      const int g = s * 2 + sub;
      if (g + 2 < 32) loadA(g + 2, Af[(g + 2) % 3]);
      const bf16x8* af = Af[g % 3];
      __builtin_amdgcn_s_setprio(1);
#pragma unroll
      for (int tn = 0; tn < 8; tn++) {
        bf16x8 bfv = *(const bf16x8*)
            &bs[(sub * 4 + quad) * 1024 + (tn * 16 + l15) * 8];
#pragma unroll
        for (int tm = 0; tm < 4; tm++)
          acc[tm][tn] = __builtin_amdgcn_mfma_f32_16x16x32_bf16(
              af[tm], bfv, acc[tm][tn], 0, 0, 0);
      }
      __builtin_amdgcn_s_setprio(0);
    }
    // publish stage(s+1) retirement (counted; stages s+2,s+3 + A stay
    // in flight across the barrier), drain own ds_reads of Bs[s&3].
    asm volatile("s_waitcnt vmcnt(16) lgkmcnt(0)" ::: "memory");
    __builtin_amdgcn_sched_barrier(0);
    asm volatile("s_barrier" ::: "memory");
  }

  const int t3 = n0 >> 10;              // block-uniform: 0=Q,1=K,2=V
  if (t3 < 2) {
    // ---- Q/K scatter to head-major [b*h][t][d]
    unsigned short* dst0 = (t3 == 0) ? Qh : Kh;
    const float sc = (t3 == 0) ? 0.125f : 1.0f;   // 1/sqrt(64), exact
#pragma unroll
    for (int tm = 0; tm < 4; tm++)
#pragma unroll
      for (int tn = 0; tn < 8; tn++) {
        int colb = n0 + tn * 16;
        int hh = (colb >> 6) & 15;
        int dd = (colb & 63) + l15;
#pragma unroll
        for (int r = 0; r < 4; r++) {
          int row = m0 + w * 64 + tm * 16 + quad * 4 + r;
          int b = row >> 11, tt = row & 2047;
          dst0[((size_t)((b * 16 + hh) * 2048 + tt)) * 64 + dd] =
              f2bf(acc[tm][tn][r] * sc);
        }
      }
  } else {
    // ---- V: per-wave LDS transpose -> Vt [bh][tc][d 64][tin 64]
    unsigned short* T = &Bs[0][0] + w * 4608;            // 64x72 tile/wave
    const int b    = (m0 + w * 64) >> 11;
    const int tc_g = ((m0 & 2047) >> 6) + w;
    const int h0   = (n0 >> 6) & 15;
#pragma unroll
    for (int hp = 0; hp < 2; hp++) {
#pragma unroll
      for (int tnl = 0; tnl < 4; tnl++)
#pragma unroll
        for (int tm = 0; tm < 4; tm++)
#pragma unroll
          for (int r = 0; r < 4; r++)
            T[(tnl * 16 + l15) * 72 + tm * 16 + quad * 4 + r] =
                f2bf(acc[tm][hp * 4 + tnl][r]);
      asm volatile("s_waitcnt lgkmcnt(0)" ::: "memory");  // wave-private
      const size_t base =
          ((size_t)((b * 16 + h0 + hp) * 32 + tc_g)) * 4096;
#pragma unroll
      for (int i = 0; i < 8; i++) {
        int d   = i * 8 + (lane >> 3);
        int tin = (lane & 7) * 8;
        bf16x8 v = *(const bf16x8*)&T[d * 72 + tin];
        *(bf16x8*)&Vt[base + (size_t)d * 64 + tin] = v;   // coalesced 1KB
      }
    }
  }
}

// ---------------------------------------------------------------------------
// Proj GEMM (round 14): same deep-pipelined BK=64 quad-buffer K-loop.
// Per-step ops: stage 4 cp16, A-prefetch 4 -> later-region guarantee
// after stage(s+1) is 16 mid-loop (N=12), but only 8 at s>=14 (N=8).
// ---------------------------------------------------------------------------
__global__ __launch_bounds__(256, 2)
void gemm_proj(const unsigned short* __restrict__ Apk,
               const unsigned short* __restrict__ Bw,
               float* __restrict__ Co) {
  __shared__ __align__(16) unsigned short Bs[4][8192];

  const int id   = blockIdx.x;
  const int xcd  = id & 7;
  const int slot = id >> 3;        // 0..63
  const int mloc = slot >> 3;      // 0..7
  const int nloc = slot & 7;       // 0..7
  const int m0 = (xcd * 8 + mloc) * 128;
  const int n0 = nloc * 128;

  const int tid  = threadIdx.x;
  const int w    = tid >> 6;
  const int lane = tid & 63;
  const int quad = lane >> 4;
  const int l15  = lane & 15;

  f32x4 acc[2][8];
#pragma unroll
  for (int i = 0; i < 2; i++)
#pragma unroll
    for (int j = 0; j < 8; j++) acc[i][j] = (f32x4)0.0f;

  const unsigned short* abase =
      Apk + ((size_t)((m0 >> 4) + w * 2) * 32) * 512 + lane * 8;

  auto stageB = [&](int k0, unsigned short* bs) {
#pragma unroll
    for (int i = 0; i < 4; i++) {
      int idx  = w + 4 * i;
      int kc   = idx >> 1;
      int half = idx & 1;
      async_cp16(Bw + (size_t)(n0 + half * 64 + lane) * 1024 + k0 + kc * 8,
                 &bs[kc * 1024 + half * 512]);
    }
  };

  bf16x8 Af[3][2];                 // depth-2 A prefetch ring
  auto loadA = [&](int g, bf16x8* fr) {
#pragma unroll
    for (int tm = 0; tm < 2; tm++)
      fr[tm] = *(const bf16x8*)(abase + ((size_t)(tm * 32 + g)) * 512);
  };

  loadA(0, Af[0]);
  loadA(1, Af[1]);
  stageB(0,   Bs[0]);
  stageB(64,  Bs[1]);
  stageB(128, Bs[2]);
  asm volatile("s_waitcnt vmcnt(0)" ::: "memory");
  __builtin_amdgcn_sched_barrier(0);
  asm volatile("s_barrier" ::: "memory");

#pragma unroll
  for (int s = 0; s < 16; s++) {
    const unsigned short* bs = Bs[s & 3];
    if (s + 3 < 16) stageB((s + 3) * 64, Bs[(s + 3) & 3]);
#pragma unroll
    for (int sub = 0; sub < 2; sub++) {
      const int g = s * 2 + sub;
      if (g + 2 < 32) loadA(g + 2, Af[(g + 2) % 3]);
      const bf16x8* af = Af[g % 3];
      __builtin_amdgcn_s_setprio(1);
#pragma unroll
      for (int tn = 0; tn < 8; tn++) {
        bf16x8 bfv = *(const bf16x8*)
            &bs[(sub * 4 + quad) * 1024 + (tn * 16 + l15) * 8];
#pragma unroll
        for (int tm = 0; tm < 2; tm++)
          acc[tm][tn] = __builtin_amdgcn_mfma_f32_16x16x32_bf16(
              af[tm], bfv, acc[tm][tn], 0, 0, 0);
      }
      __builtin_amdgcn_s_setprio(0);
    }
    if (s < 14)
      asm volatile("s_waitcnt vmcnt(12) lgkmcnt(0)" ::: "memory");
    else
      asm volatile("s_waitcnt vmcnt(8) lgkmcnt(0)" ::: "memory");
    __builtin_amdgcn_sched_barrier(0);
    asm volatile("s_barrier" ::: "memory");
  }

#pragma unroll
  for (int tm = 0; tm < 2; tm++)
#pragma unroll
    for (int tn = 0; tn < 8; tn++)
#pragma unroll
      for (int r = 0; r < 4; r++) {
        int row = m0 + w * 32 + tm * 16 + quad * 4 + r;
        int col = n0 + tn * 16 + l15;
        Co[(size_t)row * 1024 + col] = acc[tm][tn][r];
      }
}

// ---------------------------------------------------------------------------
// MFMA sliding-window flash attention, single-stage (r9-validated).
// ---------------------------------------------------------------------------
__global__ __launch_bounds__(256, 2)
void attn_mfma(const unsigned short* __restrict__ Qh,
               const unsigned short* __restrict__ Kh,
               const unsigned short* __restrict__ Vt,
               unsigned short* __restrict__ Ypk) {
  __shared__ __align__(16) unsigned short SH[40960];   // 80 KB

  const int tid  = threadIdx.x;
  const int w    = tid >> 6;
  const int lane = tid & 63;
  const int quad = lane >> 4;
  const int l15  = lane & 15;
  const int q0 = blockIdx.x * 64;
  const int bh = blockIdx.y;

  const int c0 = (q0 >= 256) ? 0 : (4 - (q0 >> 6));

  const unsigned short* Qg = Qh + ((size_t)bh * 2048 + q0) * 64;
  bf16x8 Qf[2];
#pragma unroll
  for (int fs = 0; fs < 2; fs++)
    Qf[fs] = *(const bf16x8*)(Qg + (w * 16 + l15) * 64 + fs * 32 + quad * 8);

  const unsigned short* Kg = Kh + (size_t)bh * 2048 * 64;
  const unsigned short* Vg = Vt + (size_t)bh * 32 * 4096;
  for (int ch = c0; ch < 5; ch++) {
    int sc = q0 - 256 + ch * 64;
#pragma unroll
    for (int i = 0; i < 2; i++) {
      int kc = w * 2 + i;
      async_cp16(Kg + (size_t)(sc + lane) * 64 + kc * 8,
                 &SH[ch * 4096 + kc * 512]);
      async_cp16(Vg + (size_t)(sc >> 6) * 4096 + lane * 64 + kc * 8,
                 &SH[20480 + ch * 4096 + kc * 512]);
    }
  }
  __syncthreads();

  f32x4 S[5][4];
#pragma unroll
  for (int ch = 0; ch < 5; ch++)
#pragma unroll
    for (int tn = 0; tn < 4; tn++) S[ch][tn] = (f32x4)0.0f;

#pragma unroll
  for (int ch = 0; ch < 5; ch++) {
    if (ch < c0) continue;
#pragma unroll
    for (int ks = 0; ks < 2; ks++) {
      int kc = ks * 4 + quad;
#pragma unroll
      for (int tn = 0; tn < 4; tn++) {
        bf16x8 bk = *(const bf16x8*)
            &SH[ch * 4096 + kc * 512 + (tn * 16 + l15) * 8];
        S[ch][tn] = __builtin_amdgcn_mfma_f32_16x16x32_bf16(
            Qf[ks], bk, S[ch][tn], 0, 0, 0);
      }
    }
  }

  const int qb = q0 + w * 16 + quad * 4;
  if (c0 == 0) {
#pragma unroll
    for (int tn = 0; tn < 4; tn++) {
      int j = q0 - 256 + tn * 16 + l15;
#pragma unroll
      for (int r = 0; r < 4; r++)
        if (qb + r > j + (WW - 1)) S[0][tn][r] = -__builtin_inff();
    }
  }
#pragma unroll
  for (int tn = 0; tn < 4; tn++) {
    int j = q0 + tn * 16 + l15;
#pragma unroll
    for (int r = 0; r < 4; r++)
      if (j > qb + r) S[4][tn][r] = -__builtin_inff();
  }

  float mrow[4], lrow[4];
#pragma unroll
  for (int r = 0; r < 4; r++) mrow[r] = -__builtin_inff();
#pragma unroll
  for (int ch = 0; ch < 5; ch++) {
    if (ch < c0) continue;
#pragma unroll
    for (int tn = 0; tn < 4; tn++)
#pragma unroll
      for (int r = 0; r < 4; r++)
        mrow[r] = fmaxf(mrow[r], S[ch][tn][r]);
  }
#pragma unroll
  for (int off = 1; off < 16; off <<= 1)
#pragma unroll
    for (int r = 0; r < 4; r++)
      mrow[r] = fmaxf(mrow[r], __shfl_xor(mrow[r], off));

#pragma unroll
  for (int r = 0; r < 4; r++) lrow[r] = 0.0f;
#pragma unroll
  for (int ch = 0; ch < 5; ch++) {
    if (ch < c0) continue;
#pragma unroll
    for (int tn = 0; tn < 4; tn++)
#pragma unroll
      for (int r = 0; r < 4; r++) {
        float e = __expf(S[ch][tn][r] - mrow[r]);
        S[ch][tn][r] = e;
        lrow[r] += e;
      }
  }
#pragma unroll
  for (int off = 1; off < 16; off <<= 1)
#pragma unroll
    for (int r = 0; r < 4; r++) lrow[r] += __shfl_xor(lrow[r], off);

  __syncthreads();   // all K reads done before Ps aliases the K region

  f32x4 Oacc[4];
#pragma unroll
  for (int td = 0; td < 4; td++) Oacc[td] = (f32x4)0.0f;

#pragma unroll
  for (int ch = 0; ch < 5; ch++) {
    if (ch < c0) continue;
    unsigned short* Ps = SH + (ch & 1) * 4608;
#pragma unroll
    for (int tn = 0; tn < 4; tn++)
#pragma unroll
      for (int r = 0; r < 4; r++)
        Ps[(w * 16 + quad * 4 + r) * 68 + tn * 16 + l15] = f2bf(S[ch][tn][r]);
    asm volatile("s_waitcnt lgkmcnt(0)" ::: "memory");
#pragma unroll
    for (int ks = 0; ks < 2; ks++) {
      int off = (w * 16 + l15) * 68 + ks * 32 + quad * 8;
      bf16x4 plo = *(const bf16x4*)&Ps[off];
      bf16x4 phi = *(const bf16x4*)&Ps[off + 4];
      bf16x8 ap = __builtin_shufflevector(plo, phi, 0, 1, 2, 3, 4, 5, 6, 7);
      int kc = ks * 4 + quad;
#pragma unroll
      for (int td = 0; td < 4; td++) {
        bf16x8 bv = *(const bf16x8*)
            &SH[20480 + ch * 4096 + kc * 512 + (td * 16 + l15) * 8];
        Oacc[td] = __builtin_amdgcn_mfma_f32_16x16x32_bf16(
            ap, bv, Oacc[td], 0, 0, 0);
      }
    }
  }

  const int b = bh >> 4, h = bh & 15;
  float inv[4];
#pragma unroll
  for (int r = 0; r < 4; r++) inv[r] = 1.0f / lrow[r];
  unsigned short* Ot = SH + 10240;
#pragma unroll
  for (int td = 0; td < 4; td++)
#pragma unroll
    for (int r = 0; r < 4; r++)
      Ot[(w * 16 + quad * 4 + r) * 72 + td * 16 + l15] =
          f2bf(Oacc[td][r] * inv[r]);
  asm volatile("s_waitcnt lgkmcnt(0)" ::: "memory");
  const size_t rt = (size_t)((b * 2048 + q0) >> 4) + w;
#pragma unroll
  for (int f = 0; f < 2; f++) {
    bf16x8 fr = *(const bf16x8*)&Ot[(w * 16 + l15) * 72 + f * 32 + quad * 8];
    *(bf16x8*)&Ypk[(rt * 32 + h * 2 + f) * 512 + lane * 8] = fr;
  }
}

// ---------------------------------------------------------------------------
extern "C" void kernel_launch(void* const* d_in, const int* in_sizes, int n_in,
                              void* d_out, int out_size, void* d_ws, size_t ws_size,
                              hipStream_t stream) {
  const float* x     = (const float*)d_in[0];
  const float* wqkv  = (const float*)d_in[1];
  const float* wproj = (const float*)d_in[2];
  float* out = (float*)d_out;

  char* ws = (char*)d_ws;
  // [0,16M)   Apk (packed x)
  // [16,22M)  Wqkv bf16   [22,24M) Wproj bf16
  // [24,40M)  Qh   [40,56M) Kh   [56,72M) Vt   [72,88M) Ypk (packed y)
  unsigned short* apk    = (unsigned short*)(ws);
  unsigned short* wqkvb  = (unsigned short*)(ws + (size_t)16 * 1024 * 1024);
  unsigned short* wprojb = (unsigned short*)(ws + (size_t)22 * 1024 * 1024);
  unsigned short* qh     = (unsigned short*)(ws + (size_t)24 * 1024 * 1024);
  unsigned short* kh     = (unsigned short*)(ws + (size_t)40 * 1024 * 1024);
  unsigned short* vt     = (unsigned short*)(ws + (size_t)56 * 1024 * 1024);
  unsigned short* ypk    = (unsigned short*)(ws + (size_t)72 * 1024 * 1024);

  prep<<<4096 + 2048, 256, 0, stream>>>(
      x, wqkv, wproj, (__hip_bfloat16*)wqkvb, apk);

  // qkv = x @ Wqkv^T -> Qh/Kh (head-major) + Vt (transposed, fused)
  gemm_qkv<<<768, 256, 0, stream>>>(apk, wqkvb, qh, kh, vt);

  attn_mfma<<<dim3(TT / 64, BB * HH), 256, 0, stream>>>(
      qh, kh, vt, ypk);

  gemm_proj<<<512, 256, 0, stream>>>(ypk, wprojb, out);
}